// Round 1
// baseline (27579.926 us; speedup 1.0000x reference)
//
#include <hip/hip_runtime.h>

#define NBLK 256
#define NTHR 512
#define BB 64
#define TT 200
#define SS 1024
#define DD 512
#define VV 30
#define RS 516   // padded LDS row stride (floats) for [64][512] tiles

// workspace float offsets
#define WS_H0    0                        // [2][64][512]
#define WS_H1    (WS_H0 + 2*BB*DD)        // [2][64][512]
#define WS_H1T   (WS_H1 + 2*BB*DD)        // [2][512][64]
#define WS_GH1T  (WS_H1T + 2*DD*BB)       // [1536][64]
#define WS_CT    (WS_GH1T + 3*DD*BB)      // [512][64]
#define WS_CPART (WS_CT + DD*BB)          // [64][4][512]
#define WS_ML    (WS_CPART + BB*4*DD)     // [64][4][2]
#define WS_CTR   (WS_ML + BB*4*2)         // 1 x unsigned

#define NEG_INF (-__builtin_inff())

__global__ void zero_ctr_kernel(float* ws) {
  *(unsigned*)(ws + WS_CTR) = 0u;
}

__device__ __forceinline__ void gridbar(unsigned* ctr, unsigned target) {
  __syncthreads();
  if (threadIdx.x == 0) {
    __hip_atomic_fetch_add(ctr, 1u, __ATOMIC_RELEASE, __HIP_MEMORY_SCOPE_AGENT);
    while (__hip_atomic_load(ctr, __ATOMIC_RELAXED, __HIP_MEMORY_SCOPE_AGENT) < target)
      __builtin_amdgcn_s_sleep(1);
    (void)__hip_atomic_load(ctr, __ATOMIC_ACQUIRE, __HIP_MEMORY_SCOPE_AGENT);
  }
  __syncthreads();
}

__device__ __forceinline__ float dot4(float4 a, float4 b) {
  return a.x*b.x + a.y*b.y + a.z*b.z + a.w*b.w;
}
__device__ __forceinline__ float sigmoidf_(float x) { return 1.f/(1.f + __expf(-x)); }

__device__ __forceinline__ void stage_h(float* TILE, const float* __restrict__ src, int tid) {
  #pragma unroll 2
  for (int i = tid; i < BB*128; i += NTHR) {
    const int row = i >> 7, k4 = i & 127;
    *(float4*)&TILE[row*RS + k4*4] = *(const float4*)&src[(size_t)row*DD + k4*4];
  }
}

__launch_bounds__(NTHR, 1)
__global__ void speller_kernel(const float* __restrict__ h_init,
                               const int*   __restrict__ targets,
                               const float* __restrict__ mem,
                               const float* __restrict__ W_ih0,
                               const float* __restrict__ W_hh0,
                               const float* __restrict__ b_ih0,
                               const float* __restrict__ b_hh0,
                               const float* __restrict__ W_ih1,
                               const float* __restrict__ W_hh1,
                               const float* __restrict__ b_ih1,
                               const float* __restrict__ b_hh1,
                               const float* __restrict__ W_out,
                               const float* __restrict__ W_tok,
                               const float* __restrict__ b_tok,
                               float*       __restrict__ out,
                               float*       __restrict__ ws)
{
  __shared__ float SM[35272];
  float* const TILE = SM;           // 64*516 = 33024
  float* const QL   = SM + 33024;   // 512
  float* const PSC  = SM + 33536;   // 8*64
  float* const WVL  = SM + 34048;   // 64
  float* const BC   = SM + 34112;   // 8
  float* const DOTS = SM + 34120;   // 18*64

  const int tid  = threadIdx.x;
  const int bid  = blockIdx.x;
  const int lane = tid & 63;
  const int wv   = tid >> 6;

  float* const h0b   = ws + WS_H0;
  float* const h1b   = ws + WS_H1;
  float* const h1T   = ws + WS_H1T;
  float* const gh1T  = ws + WS_GH1T;
  float* const cT    = ws + WS_CT;
  float* const cpart = ws + WS_CPART;
  float* const mlb   = ws + WS_ML;
  unsigned* const ctr = (unsigned*)(ws + WS_CTR);

  // copy initial hidden state into parity-0 buffers
  for (int i = bid*NTHR + tid; i < BB*DD; i += NBLK*NTHR) {
    h0b[i] = h_init[i];
    h1b[i] = h_init[BB*DD + i];
  }
  unsigned nbar = 0;
  gridbar(ctr, (++nbar) * NBLK);

  for (int t = 0; t <= TT; ++t) {
    const int p = t & 1, pn = p ^ 1;

    // ---------- slot 1: A = GRU0 triplets + gh1 (blocks 0..191) | D = combine partials (192..255)
    if (bid < 192) {
      if (t < TT) {
        if (bid < 96) {
          stage_h(TILE, h0b + p*BB*DD, tid);
          __syncthreads();
          const int ts = (bid*DD)/96, te = ((bid+1)*DD)/96;
          const int ncol = (te - ts)*3;
          int cid[3]; int nc = 0;
          for (int ci = wv; ci < ncol; ci += 8) if (nc < 3) cid[nc++] = ci;
          const float* wr0 = W_hh0; const float* wr1 = W_hh0; const float* wr2 = W_hh0;
          if (nc > 0) wr0 = W_hh0 + (size_t)__builtin_amdgcn_readfirstlane((cid[0]%3)*DD + ts + cid[0]/3) * DD;
          if (nc > 1) wr1 = W_hh0 + (size_t)__builtin_amdgcn_readfirstlane((cid[1]%3)*DD + ts + cid[1]/3) * DD;
          if (nc > 2) wr2 = W_hh0 + (size_t)__builtin_amdgcn_readfirstlane((cid[2]%3)*DD + ts + cid[2]/3) * DD;
          float a0 = 0.f, a1 = 0.f, a2 = 0.f;
          #pragma unroll 4
          for (int kq = 0; kq < 128; ++kq) {
            const float4 hv = *(const float4*)&TILE[lane*RS + kq*4];
            a0 += dot4(hv, *(const float4*)&wr0[kq*4]);
            a1 += dot4(hv, *(const float4*)&wr1[kq*4]);
            a2 += dot4(hv, *(const float4*)&wr2[kq*4]);
          }
          if (nc > 0) DOTS[cid[0]*64 + lane] = a0;
          if (nc > 1) DOTS[cid[1]*64 + lane] = a1;
          if (nc > 2) DOTS[cid[2]*64 + lane] = a2;
          __syncthreads();
          const int tix = (t == 0) ? 0 : (t - 1);
          for (int it = tid; it < (te - ts)*BB; it += NTHR) {
            const int dl = it >> 6, b_ = it & 63, d = ts + dl;
            const int tok = targets[b_*TT + tix];
            const float gir = W_ih0[(0*DD + d)*VV + tok] + b_ih0[0*DD + d];
            const float giz = W_ih0[(1*DD + d)*VV + tok] + b_ih0[1*DD + d];
            const float gin = W_ih0[(2*DD + d)*VV + tok] + b_ih0[2*DD + d];
            const float ghr = DOTS[(dl*3+0)*64 + b_] + b_hh0[0*DD + d];
            const float ghz = DOTS[(dl*3+1)*64 + b_] + b_hh0[1*DD + d];
            const float ghn = DOTS[(dl*3+2)*64 + b_] + b_hh0[2*DD + d];
            const float r = sigmoidf_(gir + ghr);
            const float z = sigmoidf_(giz + ghz);
            const float n = tanhf(gin + r*ghn);
            h0b[pn*BB*DD + b_*DD + d] = (1.f - z)*n + z*TILE[b_*RS + d];
          }
        } else {
          stage_h(TILE, h1b + p*BB*DD, tid);
          __syncthreads();
          const int r0 = (bid - 96)*16 + wv*2;
          const float* wr0 = W_hh1 + (size_t)__builtin_amdgcn_readfirstlane(r0)   * DD;
          const float* wr1 = W_hh1 + (size_t)__builtin_amdgcn_readfirstlane(r0+1) * DD;
          float a0 = 0.f, a1 = 0.f;
          #pragma unroll 4
          for (int kq = 0; kq < 128; ++kq) {
            const float4 hv = *(const float4*)&TILE[lane*RS + kq*4];
            a0 += dot4(hv, *(const float4*)&wr0[kq*4]);
            a1 += dot4(hv, *(const float4*)&wr1[kq*4]);
          }
          gh1T[(size_t)r0*BB + lane]     = a0 + b_hh1[r0];
          gh1T[(size_t)(r0+1)*BB + lane] = a1 + b_hh1[r0+1];
        }
      }
    } else {
      if (t >= 1) {
        const int b_ = bid - 192, te_ = t - 1;
        const float m0 = mlb[(b_*4+0)*2], l0 = mlb[(b_*4+0)*2+1];
        const float m1 = mlb[(b_*4+1)*2], l1 = mlb[(b_*4+1)*2+1];
        const float m2 = mlb[(b_*4+2)*2], l2 = mlb[(b_*4+2)*2+1];
        const float m3 = mlb[(b_*4+3)*2], l3 = mlb[(b_*4+3)*2+1];
        const float M = fmaxf(fmaxf(m0,m1), fmaxf(m2,m3));
        const float w0 = __expf(m0-M), w1 = __expf(m1-M), w2 = __expf(m2-M), w3 = __expf(m3-M);
        const float invL = 1.f/(w0*l0 + w1*l1 + w2*l2 + w3*l3);
        const float ck = (w0*cpart[(size_t)(b_*4+0)*DD + tid] + w1*cpart[(size_t)(b_*4+1)*DD + tid]
                        + w2*cpart[(size_t)(b_*4+2)*DD + tid] + w3*cpart[(size_t)(b_*4+3)*DD + tid]) * invL;
        cT[(size_t)tid*BB + b_] = ck;
        if (tid < VV) out[((size_t)b_*TT + te_)*VV + tid] = b_tok[tid];
      }
    }
    gridbar(ctr, (++nbar) * NBLK);

    // ---------- slot 2: B = GRU1 (blocks 0..191) | E = attn_h + logits (192..255)
    if (bid < 192) {
      if (t < TT) {
        stage_h(TILE, h0b + pn*BB*DD, tid);
        __syncthreads();
        const int ts = (bid*DD)/192, te = ((bid+1)*DD)/192;
        const int ncol = (te - ts)*3;
        int cid[2]; int nc = 0;
        for (int ci = wv; ci < ncol; ci += 8) if (nc < 2) cid[nc++] = ci;
        const float* wr0 = W_ih1; const float* wr1 = W_ih1;
        if (nc > 0) wr0 = W_ih1 + (size_t)__builtin_amdgcn_readfirstlane((cid[0]%3)*DD + ts + cid[0]/3) * DD;
        if (nc > 1) wr1 = W_ih1 + (size_t)__builtin_amdgcn_readfirstlane((cid[1]%3)*DD + ts + cid[1]/3) * DD;
        float a0 = 0.f, a1 = 0.f;
        #pragma unroll 4
        for (int kq = 0; kq < 128; ++kq) {
          const float4 hv = *(const float4*)&TILE[lane*RS + kq*4];
          a0 += dot4(hv, *(const float4*)&wr0[kq*4]);
          a1 += dot4(hv, *(const float4*)&wr1[kq*4]);
        }
        if (nc > 0) DOTS[cid[0]*64 + lane] = a0;
        if (nc > 1) DOTS[cid[1]*64 + lane] = a1;
        __syncthreads();
        for (int it = tid; it < (te - ts)*BB; it += NTHR) {
          const int dl = it >> 6, b_ = it & 63, d = ts + dl;
          const float gir = DOTS[(dl*3+0)*64 + b_] + b_ih1[0*DD + d];
          const float giz = DOTS[(dl*3+1)*64 + b_] + b_ih1[1*DD + d];
          const float gin = DOTS[(dl*3+2)*64 + b_] + b_ih1[2*DD + d];
          const float ghr = gh1T[(size_t)(0*DD + d)*BB + b_];
          const float ghz = gh1T[(size_t)(1*DD + d)*BB + b_];
          const float ghn = gh1T[(size_t)(2*DD + d)*BB + b_];
          const float r = sigmoidf_(gir + ghr);
          const float z = sigmoidf_(giz + ghz);
          const float n = tanhf(gin + r*ghn);
          const float hnew = (1.f - z)*n + z*h1b[p*BB*DD + b_*DD + d];
          h1b[pn*BB*DD + b_*DD + d] = hnew;
          h1T[(size_t)pn*DD*BB + (size_t)d*BB + b_] = hnew;
        }
      }
    } else {
      if (t >= 1) {
        const int j0 = bid - 192, o0 = j0*8, te_ = t - 1;
        const float* base = (wv < 4) ? (cT + (size_t)(wv*128)*BB)
                                     : (h1T + (size_t)p*DD*BB + (size_t)((wv-4)*128)*BB);
        const float* wrow[8];
        #pragma unroll
        for (int c = 0; c < 8; ++c)
          wrow[c] = W_out + (size_t)__builtin_amdgcn_readfirstlane(o0 + c) * (2*DD) + wv*128;
        float ac[8] = {0.f,0.f,0.f,0.f,0.f,0.f,0.f,0.f};
        for (int jj = 0; jj < 128; ++jj) {
          const float vvv = base[(size_t)jj*BB + lane];
          #pragma unroll
          for (int c = 0; c < 8; ++c) ac[c] += wrow[c][jj] * vvv;
        }
        #pragma unroll
        for (int c = 0; c < 8; ++c) TILE[(wv*8 + c)*64 + lane] = ac[c];
        __syncthreads();
        {
          const int c = tid >> 6;
          float s_ = 0.f;
          #pragma unroll
          for (int w = 0; w < 8; ++w) s_ += TILE[(w*8 + c)*64 + lane];
          TILE[4096 + c*64 + lane] = tanhf(s_);
        }
        __syncthreads();
        for (int it = tid; it < BB*VV; it += NTHR) {
          const int v = it >> 6, b_ = it & 63;
          const float4 wt0 = *(const float4*)&W_tok[v*DD + o0];
          const float4 wt1 = *(const float4*)&W_tok[v*DD + o0 + 4];
          const float s_ = TILE[4096 + 0*64 + b_]*wt0.x + TILE[4096 + 1*64 + b_]*wt0.y
                         + TILE[4096 + 2*64 + b_]*wt0.z + TILE[4096 + 3*64 + b_]*wt0.w
                         + TILE[4096 + 4*64 + b_]*wt1.x + TILE[4096 + 5*64 + b_]*wt1.y
                         + TILE[4096 + 6*64 + b_]*wt1.z + TILE[4096 + 7*64 + b_]*wt1.w;
          atomicAdd(&out[((size_t)b_*TT + te_)*VV + v], s_);
        }
      }
    }
    if (t == TT) break;
    gridbar(ctr, (++nbar) * NBLK);

    // ---------- slot 3: C1 = flash attention partials (all 256 blocks)
    {
      const int b_ = bid >> 2, chunk = bid & 3;
      const int s0 = chunk * 256;
      const float* q = h1b + pn*BB*DD + (size_t)b_*DD;
      for (int i = tid; i < DD; i += NTHR) QL[i] = q[i];
      float m_run = NEG_INF, l_run = 0.f, cacc = 0.f;   // this thread owns k = tid
      for (int tile = 0; tile < 4; ++tile) {
        __syncthreads();
        const float* src = mem + ((size_t)b_*SS + s0 + tile*64) * DD;
        #pragma unroll 2
        for (int i = tid; i < 64*128; i += NTHR) {
          const int row = i >> 7, k4 = i & 127;
          *(float4*)&TILE[row*RS + k4*4] = *(const float4*)&src[(size_t)row*DD + k4*4];
        }
        __syncthreads();
        float sc = 0.f;
        #pragma unroll 4
        for (int kq = 0; kq < 16; ++kq) {
          const float4 hv = *(const float4*)&TILE[lane*RS + wv*64 + kq*4];
          const float4 qv = *(const float4*)&QL[wv*64 + kq*4];
          sc += dot4(hv, qv);
        }
        PSC[wv*64 + lane] = sc;
        __syncthreads();
        if (wv == 0) {
          float tot = 0.f;
          #pragma unroll
          for (int w = 0; w < 8; ++w) tot += PSC[w*64 + lane];
          float mx = tot;
          #pragma unroll
          for (int off = 32; off; off >>= 1) mx = fmaxf(mx, __shfl_xor(mx, off));
          const float m_new = fmaxf(m_run, mx);
          const float wl = __expf(tot - m_new);
          WVL[lane] = wl;
          float ls = wl;
          #pragma unroll
          for (int off = 32; off; off >>= 1) ls += __shfl_xor(ls, off);
          if (lane == 0) { BC[0] = m_new; BC[1] = ls; }
        }
        __syncthreads();
        const float m_new = BC[0], l_tile = BC[1];
        const float scale = __expf(m_run - m_new);
        l_run = l_run * scale + l_tile;
        m_run = m_new;
        cacc *= scale;
        #pragma unroll 4
        for (int s = 0; s < 64; ++s) cacc += WVL[s] * TILE[s*RS + tid];
      }
      cpart[(size_t)(b_*4 + chunk)*DD + tid] = cacc;
      if (tid == 0) { mlb[(b_*4+chunk)*2] = m_run; mlb[(b_*4+chunk)*2+1] = l_run; }
    }
    gridbar(ctr, (++nbar) * NBLK);
  }
}

extern "C" void kernel_launch(void* const* d_in, const int* in_sizes, int n_in,
                              void* d_out, int out_size, void* d_ws, size_t ws_size,
                              hipStream_t stream) {
  const float* h_init = (const float*)d_in[0];
  const int*   targets= (const int*)d_in[1];
  const float* mem    = (const float*)d_in[2];
  const float* W_ih0  = (const float*)d_in[3];
  const float* W_hh0  = (const float*)d_in[4];
  const float* b_ih0  = (const float*)d_in[5];
  const float* b_hh0  = (const float*)d_in[6];
  const float* W_ih1  = (const float*)d_in[7];
  const float* W_hh1  = (const float*)d_in[8];
  const float* b_ih1  = (const float*)d_in[9];
  const float* b_hh1  = (const float*)d_in[10];
  const float* W_out  = (const float*)d_in[11];
  const float* W_tok  = (const float*)d_in[12];
  const float* b_tok  = (const float*)d_in[13];
  float* out = (float*)d_out;
  float* ws  = (float*)d_ws;

  hipLaunchKernelGGL(zero_ctr_kernel, dim3(1), dim3(1), 0, stream, ws);

  void* args[] = { (void*)&h_init, (void*)&targets, (void*)&mem,
                   (void*)&W_ih0, (void*)&W_hh0, (void*)&b_ih0, (void*)&b_hh0,
                   (void*)&W_ih1, (void*)&W_hh1, (void*)&b_ih1, (void*)&b_hh1,
                   (void*)&W_out, (void*)&W_tok, (void*)&b_tok,
                   (void*)&out, (void*)&ws };
  hipError_t err = hipLaunchCooperativeKernel((const void*)speller_kernel,
                                              dim3(NBLK), dim3(NTHR), args, 0, stream);
  if (err != hipSuccess) {
    // fallback: plain launch (grid <= CU count, 1 block/CU -> co-resident)
    hipLaunchKernelGGL(speller_kernel, dim3(NBLK), dim3(NTHR), 0, stream,
                       h_init, targets, mem, W_ih0, W_hh0, b_ih0, b_hh0,
                       W_ih1, W_hh1, b_ih1, b_hh1, W_out, W_tok, b_tok, out, ws);
  }
}